// Round 1
// baseline (3145.849 us; speedup 1.0000x reference)
//
#include <hip/hip_runtime.h>
#include <hip/hip_bf16.h>

typedef unsigned short u16;
typedef __bf16 bf16x8 __attribute__((ext_vector_type(8)));
typedef float f32x4 __attribute__((ext_vector_type(4)));
typedef u16 u16x8 __attribute__((ext_vector_type(8)));

#define FDIM 2048
#define B16 16
#define VSTR 2056          // 2048 + 8 pad (bf16 elems) -> row stride 4112B, 16B aligned
#define NBLK 128
#define NSTEP 63

__device__ __forceinline__ u16 f2b(float x) {
    __hip_bfloat16 h = __float2bfloat16(x);
    return __builtin_bit_cast(u16, h);
}
__device__ __forceinline__ float b2f(u16 u) {
    __hip_bfloat16 h = __builtin_bit_cast(__hip_bfloat16, u);
    return __bfloat162float(h);
}
__device__ __forceinline__ float sigm(float x) { return 1.0f / (1.0f + __expf(-x)); }
__device__ __forceinline__ float tanh_f(float x) { return 1.0f - 2.0f / (__expf(2.0f * x) + 1.0f); }

// ---------------- weight fp32 -> bf16 ----------------
__global__ void k_convert(const float* __restrict__ s0, const float* __restrict__ s1,
                          const float* __restrict__ s2, const float* __restrict__ s3,
                          u16* __restrict__ dst) {
    const size_t n1 = (size_t)4 * FDIM * FDIM;      // elems per matrix (8192*2048)
    const size_t n4 = n1 / 4;
    const float* src = (blockIdx.y == 0) ? s0 : (blockIdx.y == 1) ? s1 : (blockIdx.y == 2) ? s2 : s3;
    u16* d = dst + (size_t)blockIdx.y * n1;
    size_t stride = (size_t)gridDim.x * blockDim.x;
    for (size_t i = (size_t)blockIdx.x * blockDim.x + threadIdx.x; i < n4; i += stride) {
        float4 v = ((const float4*)src)[i];
        ushort4 o;
        o.x = f2b(v.x); o.y = f2b(v.y); o.z = f2b(v.z); o.w = f2b(v.w);
        ((ushort4*)d)[i] = o;
    }
}

__global__ void k_bias(const float* __restrict__ bi0, const float* __restrict__ bh0,
                       const float* __restrict__ bi1, const float* __restrict__ bh1,
                       float* __restrict__ bias0, float* __restrict__ bias1) {
    int i = blockIdx.x * blockDim.x + threadIdx.x;
    if (i < 4 * FDIM) {
        bias0[i] = bi0[i] + bh0[i];
        bias1[i] = bi1[i] + bh1[i];
    }
}

// ---------------- input 1x1 conv -> seq layout [t][b][w*64+cb] (bf16) ----------------
__global__ __launch_bounds__(256) void k_seqprep(const float* __restrict__ x,
                                                 const float* __restrict__ w_in,
                                                 const float* __restrict__ b_in,
                                                 u16* __restrict__ seqb) {
    int h = blockIdx.x >> 4, b = blockIdx.x & 15;
    __shared__ float xs[256][32];     // x[b][c][h][w]
    __shared__ float wl[64][257];     // w_in padded
    int tid = threadIdx.x;
    for (int i = tid; i < 256 * 32; i += 256) {
        int c = i >> 5, w = i & 31;
        xs[c][w] = x[(((size_t)b * 256 + c) * 32 + h) * 32 + w];
    }
    for (int i = tid; i < 64 * 256; i += 256) {
        int cb = i >> 8, c = i & 255;
        wl[cb][c] = w_in[i];
    }
    __syncthreads();
    int w = (tid * 8) >> 6, cb0 = (tid * 8) & 63;
    float acc[8];
#pragma unroll
    for (int j = 0; j < 8; ++j) acc[j] = b_in[cb0 + j];
    for (int c = 0; c < 256; ++c) {
        float xv = xs[c][w];
#pragma unroll
        for (int j = 0; j < 8; ++j) acc[j] += xv * wl[cb0 + j][c];
    }
    u16x8 o;
#pragma unroll
    for (int j = 0; j < 8; ++j) o[j] = f2b(acc[j]);
    *(u16x8*)(seqb + ((size_t)h * 16 + b) * FDIM + tid * 8) = o;
}

// ---------------- grid barrier (device-scope, monotonic counter) ----------------
__device__ __forceinline__ void gbar(unsigned* bar, unsigned target) {
    __syncthreads();
    if (threadIdx.x == 0) {
        __hip_atomic_fetch_add(bar, 1u, __ATOMIC_ACQ_REL, __HIP_MEMORY_SCOPE_AGENT);
        while (__hip_atomic_load(bar, __ATOMIC_ACQUIRE, __HIP_MEMORY_SCOPE_AGENT) < target) {
            __builtin_amdgcn_s_sleep(2);
        }
    }
    __syncthreads();
}

// stage 16x2048 bf16 operand into padded LDS (512 threads)
__device__ __forceinline__ void stage_v(u16* vbuf, const u16* __restrict__ src) {
    int t = threadIdx.x;
#pragma unroll
    for (int it = 0; it < 8; ++it) {
        int idx = it * 4096 + t * 8;
        int r = idx >> 11, c = idx & 2047;
        *(u16x8*)(vbuf + r * VSTR + c) = *(const u16x8*)(src + idx);
    }
}

// accumulate one 16x16 tile over this wave's K-half for one matrix
__device__ __forceinline__ f32x4 gemm_acc(const u16* vbuf, const u16* __restrict__ Wm,
                                          f32x4 acc, int gate, int kh, int hbase) {
    int lane = threadIdx.x & 63;
    int jloc = lane & 15;
    int koff = (lane >> 4) * 8;
    int kbase = kh * 1024;
    const u16* vp = vbuf + (lane & 15) * VSTR + kbase + koff;
    const u16* wp = Wm + ((size_t)(gate * FDIM + hbase + jloc)) * FDIM + kbase + koff;
#pragma unroll 8
    for (int k0 = 0; k0 < 1024; k0 += 32) {
        bf16x8 a = *reinterpret_cast<const bf16x8*>(vp + k0);
        bf16x8 b = *reinterpret_cast<const bf16x8*>(wp + k0);
        acc = __builtin_amdgcn_mfma_f32_16x16x32_bf16(a, b, acc, 0, 0, 0);
    }
    return acc;
}

__device__ __forceinline__ void lstm_cell(u16* vbuf, float (*gbuf)[16][16],
                                          const u16* __restrict__ Wih, const u16* __restrict__ Whh,
                                          const float* __restrict__ bias,
                                          const u16* __restrict__ xsrc, const u16* __restrict__ hsrc,
                                          float* __restrict__ cst, u16* __restrict__ hdst,
                                          u16* __restrict__ odst,
                                          unsigned* bar, unsigned target, int hbase) {
    int tid = threadIdx.x;
    int wv = tid >> 6;
    int gate = wv & 3, kh = wv >> 2;

    stage_v(vbuf, xsrc);
    __syncthreads();
    f32x4 acc = {0.f, 0.f, 0.f, 0.f};
    acc = gemm_acc(vbuf, Wih, acc, gate, kh, hbase);
    __syncthreads();
    stage_v(vbuf, hsrc);
    __syncthreads();
    acc = gemm_acc(vbuf, Whh, acc, gate, kh, hbase);

    int lane = tid & 63, jloc = lane & 15, brow = (lane >> 4) * 4;
#pragma unroll
    for (int i = 0; i < 4; ++i) gbuf[wv][brow + i][jloc] = acc[i];
    __syncthreads();

    if (tid < 256) {
        int b = tid >> 4, f = tid & 15, fg = hbase + f;
        float ig  = gbuf[0][b][f] + gbuf[4][b][f] + bias[fg];
        float fgt = gbuf[1][b][f] + gbuf[5][b][f] + bias[FDIM + fg];
        float gg  = gbuf[2][b][f] + gbuf[6][b][f] + bias[2 * FDIM + fg];
        float og  = gbuf[3][b][f] + gbuf[7][b][f] + bias[3 * FDIM + fg];
        float co = cst[(size_t)b * FDIM + fg];
        float cn = sigm(fgt) * co + sigm(ig) * tanh_f(gg);
        float hn = sigm(og) * tanh_f(cn);
        cst[(size_t)b * FDIM + fg] = cn;
        u16 hb = f2b(hn);
        hdst[(size_t)b * FDIM + fg] = hb;
        if (odst) odst[(size_t)b * FDIM + fg] = hb;
    }
    gbar(bar, target);
}

__global__ __launch_bounds__(512) void k_lstm(const u16* __restrict__ Wb,
                                              const float* __restrict__ bias0,
                                              const float* __restrict__ bias1,
                                              const u16* __restrict__ seqb,
                                              u16* __restrict__ h0, u16* __restrict__ h1,
                                              float* __restrict__ c0, float* __restrict__ c1,
                                              u16* __restrict__ seqout, unsigned* bar) {
    __shared__ u16 vbuf[16 * VSTR];
    __shared__ float gbuf[8][16][16];
    const size_t N1 = (size_t)4 * FDIM * FDIM;
    const u16* Wih0 = Wb;
    const u16* Whh0 = Wb + N1;
    const u16* Wih1 = Wb + 2 * N1;
    const u16* Whh1 = Wb + 3 * N1;
    const size_t BF = (size_t)B16 * FDIM;
    int hbase = blockIdx.x << 4;
    unsigned target = 0;

    for (int st = 0; st < NSTEP; ++st) {
        int cur = st & 1, prv = cur ^ 1;
        const u16* xs = (st < 32) ? (seqb + (size_t)st * BF) : (h1 + (size_t)prv * BF);
        target += NBLK;
        lstm_cell(vbuf, gbuf, Wih0, Whh0, bias0, xs, h0 + (size_t)prv * BF,
                  c0, h0 + (size_t)cur * BF, nullptr, bar, target, hbase);
        u16* od = (st >= 31) ? (seqout + (size_t)(st - 31) * BF) : nullptr;
        target += NBLK;
        lstm_cell(vbuf, gbuf, Wih1, Whh1, bias1, h0 + (size_t)cur * BF, h1 + (size_t)prv * BF,
                  c1, h1 + (size_t)cur * BF, od, bar, target, hbase);
    }
}

// ---------------- copy x into top half of output ----------------
__global__ void k_copyx(const float* __restrict__ x, float* __restrict__ out) {
    size_t n = (size_t)4096 * 256;    // (b,c) pairs * 256 float4
    size_t stride = (size_t)gridDim.x * blockDim.x;
    for (size_t i = (size_t)blockIdx.x * blockDim.x + threadIdx.x; i < n; i += stride) {
        size_t bc = i >> 8, r = i & 255;
        ((float4*)out)[bc * 512 + r] = ((const float4*)x)[i];
    }
}

// ---------------- output 1x1 conv into bottom half ----------------
__global__ __launch_bounds__(256) void k_convout(const u16* __restrict__ seqout,
                                                 const float* __restrict__ w_out,
                                                 const float* __restrict__ b_out,
                                                 float* __restrict__ out) {
    int s = blockIdx.x >> 4, b = blockIdx.x & 15;
    __shared__ float srow[2048];
    int tid = threadIdx.x;
    for (int i = tid; i < 2048; i += 256) srow[i] = b2f(seqout[((size_t)s * 16 + b) * FDIM + i]);
    __syncthreads();
    int o = tid;
    float bo = b_out[o];
    float wreg[64];
#pragma unroll
    for (int cb = 0; cb < 64; ++cb) wreg[cb] = w_out[o * 64 + cb];
    for (int w4 = 0; w4 < 8; ++w4) {
        float ac0 = bo, ac1 = bo, ac2 = bo, ac3 = bo;
#pragma unroll
        for (int cb = 0; cb < 64; ++cb) {
            float wv = wreg[cb];
            ac0 += srow[(w4 * 4 + 0) * 64 + cb] * wv;
            ac1 += srow[(w4 * 4 + 1) * 64 + cb] * wv;
            ac2 += srow[(w4 * 4 + 2) * 64 + cb] * wv;
            ac3 += srow[(w4 * 4 + 3) * 64 + cb] * wv;
        }
        float4 v; v.x = ac0; v.y = ac1; v.z = ac2; v.w = ac3;
        *(float4*)&out[(((size_t)b * 256 + o) * 64 + 32 + s) * 32 + w4 * 4] = v;
    }
}

extern "C" void kernel_launch(void* const* d_in, const int* in_sizes, int n_in,
                              void* d_out, int out_size, void* d_ws, size_t ws_size,
                              hipStream_t stream) {
    const float* x    = (const float*)d_in[0];
    const float* w_in = (const float*)d_in[1];
    const float* b_in = (const float*)d_in[2];
    const float* Wih0 = (const float*)d_in[3];
    const float* Whh0 = (const float*)d_in[4];
    const float* bih0 = (const float*)d_in[5];
    const float* bhh0 = (const float*)d_in[6];
    const float* Wih1 = (const float*)d_in[7];
    const float* Whh1 = (const float*)d_in[8];
    const float* bih1 = (const float*)d_in[9];
    const float* bhh1 = (const float*)d_in[10];
    const float* wout = (const float*)d_in[11];
    const float* bout = (const float*)d_in[12];
    float* out = (float*)d_out;
    char* ws = (char*)d_ws;

    const size_t N1 = (size_t)4 * FDIM * FDIM;     // 16,777,216 elems per matrix
    u16* Wb = (u16*)ws;
    size_t off = 4 * N1 * 2;                       // 134,217,728
    float* bias0 = (float*)(ws + off); off += 4 * FDIM * 4;
    float* bias1 = (float*)(ws + off); off += 4 * FDIM * 4;
    u16* seqb   = (u16*)(ws + off); off += (size_t)32 * B16 * FDIM * 2;
    u16* seqout = (u16*)(ws + off); off += (size_t)32 * B16 * FDIM * 2;
    size_t zoff = off;
    u16* h0 = (u16*)(ws + off); off += (size_t)2 * B16 * FDIM * 2;
    u16* h1 = (u16*)(ws + off); off += (size_t)2 * B16 * FDIM * 2;
    float* c0 = (float*)(ws + off); off += (size_t)B16 * FDIM * 4;
    float* c1 = (float*)(ws + off); off += (size_t)B16 * FDIM * 4;
    unsigned* bar = (unsigned*)(ws + off); off += 256;

    // zero states + barrier counter (captured in graph, replayed every call)
    hipMemsetAsync(ws + zoff, 0, off - zoff, stream);

    k_convert<<<dim3(1024, 4), 256, 0, stream>>>(Wih0, Whh0, Wih1, Whh1, Wb);
    k_bias<<<32, 256, 0, stream>>>(bih0, bhh0, bih1, bhh1, bias0, bias1);
    k_seqprep<<<512, 256, 0, stream>>>(x, w_in, b_in, seqb);
    k_lstm<<<NBLK, 512, 0, stream>>>(Wb, bias0, bias1, seqb, h0, h1, c0, c1, seqout, bar);
    k_copyx<<<2048, 256, 0, stream>>>(x, out);
    k_convout<<<512, 256, 0, stream>>>(seqout, wout, bout, out);
}

// Round 2
// 1457.129 us; speedup vs baseline: 2.1589x; 2.1589x over previous
//
#include <hip/hip_runtime.h>
#include <hip/hip_bf16.h>

typedef unsigned short u16;
typedef unsigned char uchar;
typedef unsigned long long u64;
typedef float f32x4 __attribute__((ext_vector_type(4)));
typedef u64 u64x2 __attribute__((ext_vector_type(2)));

#define FDIM 2048
#define NBLK 256
#define NSTEP 63

__device__ __forceinline__ u16 f2b(float x) {
    __hip_bfloat16 h = __float2bfloat16(x);
    return __builtin_bit_cast(u16, h);
}
__device__ __forceinline__ float b2f(u16 u) {
    __hip_bfloat16 h = __builtin_bit_cast(__hip_bfloat16, u);
    return __bfloat162float(h);
}
__device__ __forceinline__ float sigm(float x) { return 1.0f / (1.0f + __expf(-x)); }
__device__ __forceinline__ float tanh_f(float x) { return 1.0f - 2.0f / (__expf(2.0f * x) + 1.0f); }

// manual OCP e4m3 encode (RNE), saturate to 448. No NaN inputs expected.
__device__ __forceinline__ unsigned f2fp8(float x) {
    unsigned u = __builtin_bit_cast(unsigned, x);
    unsigned s = (u >> 24) & 0x80u;
    unsigned mag = u & 0x7fffffffu;
    if (mag >= 0x43E80000u) return s | 0x7Eu;          // >= 464 -> sat 448
    int e = (int)(mag >> 23) - 127;
    if (e >= -6) {
        unsigned m = mag + 0x7FFFFu + ((mag >> 20) & 1u);   // RNE into 3 mantissa bits
        unsigned e8 = (m >> 23) - 127 + 7;
        unsigned m3 = (m >> 20) & 7u;
        if (e8 >= 16u) return s | 0x7Eu;
        return s | (e8 << 3) | m3;
    }
    float ax = __builtin_bit_cast(float, mag);
    int d = (int)__builtin_rintf(ax * 512.0f);          // subnormal grid 2^-9 (d<=8 ok)
    return s | (unsigned)d;
}

__device__ __forceinline__ f32x4 mfma8(long long a, long long b, f32x4 c) {
    return __builtin_amdgcn_mfma_f32_16x16x32_fp8_fp8(a, b, c, 0, 0, 0);
}

// ---------------- weight pack: fp32 -> fp8 e4m3 (x32) in per-wave MFMA stream order ----------------
// Stream layout: for (cm, bl, gp, kh): 16 kk2-steps x 64 lanes x 16B.
// byte i of (kk2,lane): kk=2*kk2+(i>>3), e=i&7; gate=2gp+((lane&15)>>3); feat=bl*8+(lane&7);
// row=gate*2048+feat; k=kh*1024+kk*32+(lane>>4)*8+e.
__global__ __launch_bounds__(256) void k_pack(const float* __restrict__ W0, const float* __restrict__ W1,
                                              const float* __restrict__ W2, const float* __restrict__ W3,
                                              uchar* __restrict__ Wp) {
    __shared__ float lw[32][257];
    int idx = blockIdx.x;                 // [0, 8192)
    int q = idx & 3, khh = (idx >> 2) & 1, bl = (idx >> 3) & 255, cm = idx >> 11;
    const float* src = cm == 0 ? W0 : cm == 1 ? W1 : cm == 2 ? W2 : W3;
    int tid = threadIdx.x;
    int kbase = khh * 1024 + q * 256;
    for (int i = tid; i < 32 * 256; i += 256) {
        int r = i >> 8, c = i & 255;
        int gate = r >> 3, fe = r & 7;
        lw[r][c] = src[((size_t)(gate * 2048 + bl * 8 + fe)) * 2048 + kbase + c];
    }
    __syncthreads();
#pragma unroll
    for (int it = 0; it < 2; ++it) {
        int u = it * 256 + tid;           // [0,512)
        int gp = u >> 8, kk2i = (u >> 6) & 3, lane = u & 63;
        int kk2 = q * 4 + kk2i;
        unsigned wrd[4];
#pragma unroll
        for (int wi = 0; wi < 4; ++wi) {
            unsigned acc = 0;
#pragma unroll
            for (int byi = 0; byi < 4; ++byi) {
                int i2 = wi * 4 + byi;
                int kk = 2 * kk2 + (i2 >> 3), e = i2 & 7;
                int r = (2 * gp + ((lane & 15) >> 3)) * 8 + (lane & 7);
                int kl = kk * 32 + ((lane >> 4) << 3) + e - q * 256;
                acc |= f2fp8(lw[r][kl] * 32.0f) << (byi * 8);
            }
            wrd[wi] = acc;
        }
        size_t off = ((((size_t)cm * 256 + bl) * 2 + gp) * 2 + khh) * 16384 + (size_t)kk2 * 1024 + (size_t)lane * 16;
        *(uint4*)(Wp + off) = make_uint4(wrd[0], wrd[1], wrd[2], wrd[3]);
    }
}

__global__ void k_bias(const float* __restrict__ bi0, const float* __restrict__ bh0,
                       const float* __restrict__ bi1, const float* __restrict__ bh1,
                       float* __restrict__ bias0, float* __restrict__ bias1) {
    int i = blockIdx.x * blockDim.x + threadIdx.x;
    if (i < 4 * FDIM) {
        bias0[i] = bi0[i] + bh0[i];
        bias1[i] = bi1[i] + bh1[i];
    }
}

// ---------------- input 1x1 conv -> seq layout [t][b][2048] fp8 (x4) ----------------
__global__ __launch_bounds__(256) void k_seqprep(const float* __restrict__ x,
                                                 const float* __restrict__ w_in,
                                                 const float* __restrict__ b_in,
                                                 uchar* __restrict__ seqb) {
    int h = blockIdx.x >> 4, b = blockIdx.x & 15;
    __shared__ float xs[256][32];
    __shared__ float wl[64][257];
    int tid = threadIdx.x;
    for (int i = tid; i < 256 * 32; i += 256) {
        int c = i >> 5, w = i & 31;
        xs[c][w] = x[(((size_t)b * 256 + c) * 32 + h) * 32 + w];
    }
    for (int i = tid; i < 64 * 256; i += 256) {
        int cb = i >> 8, c = i & 255;
        wl[cb][c] = w_in[i];
    }
    __syncthreads();
    int w = (tid * 8) >> 6, cb0 = (tid * 8) & 63;
    float acc[8];
#pragma unroll
    for (int j = 0; j < 8; ++j) acc[j] = b_in[cb0 + j];
    for (int c = 0; c < 256; ++c) {
        float xv = xs[c][w];
#pragma unroll
        for (int j = 0; j < 8; ++j) acc[j] += xv * wl[cb0 + j][c];
    }
    unsigned lo = 0, hi2 = 0;
#pragma unroll
    for (int j = 0; j < 4; ++j) lo |= f2fp8(acc[j] * 4.0f) << (j * 8);
#pragma unroll
    for (int j = 0; j < 4; ++j) hi2 |= f2fp8(acc[4 + j] * 4.0f) << (j * 8);
    *(uint2*)(seqb + ((size_t)h * 16 + b) * FDIM + tid * 8) = make_uint2(lo, hi2);
}

// ---------------- grid barrier ----------------
__device__ __forceinline__ void gbar(unsigned* bar, unsigned target) {
    __syncthreads();
    if (threadIdx.x == 0) {
        __hip_atomic_fetch_add(bar, 1u, __ATOMIC_ACQ_REL, __HIP_MEMORY_SCOPE_AGENT);
        while (__hip_atomic_load(bar, __ATOMIC_ACQUIRE, __HIP_MEMORY_SCOPE_AGENT) < target) {
            __builtin_amdgcn_s_sleep(2);
        }
    }
    __syncthreads();
}

// stage both A-operands (fp8 [b][2048]) into granule-transposed swizzled LDS.
// slot(g,b): PAIR=g>>1; phys = PAIR*16 + (b ^ (PAIR&15)); byte = phys*16 + (g&1)*8
__device__ __forceinline__ void stageA(char* At, const uchar* __restrict__ xop, const uchar* __restrict__ hop) {
    int tid = threadIdx.x;
#pragma unroll
    for (int it = 0; it < 8; ++it) {
        int u = it * 512 + tid;              // [0,4096)
        int op = u >> 11;
        int uu = u & 2047;
        int b = uu >> 7, gp2 = uu & 127;
        const uchar* s = (op ? hop : xop) + b * 2048 + gp2 * 16;
        uint4 v = *(const uint4*)s;
        int slot = gp2 * 16 + (b ^ (gp2 & 15));
        *(uint4*)(At + (size_t)op * 32768 + (size_t)slot * 16) = v;
    }
}

__device__ __forceinline__ void do_cell(char* At, float (*gbuf)[16][16],
                                        const uchar* __restrict__ Wp, size_t so,
                                        const uchar* __restrict__ xop, const uchar* __restrict__ hop,
                                        uchar* __restrict__ hdst, u16* __restrict__ odst,
                                        const float* bia, float& cst,
                                        unsigned* bar, unsigned target, int col) {
    int tid = threadIdx.x, lane = tid & 63, w = tid >> 6;
    int m = (w >> 1) & 1;
    stageA(At, xop, hop);
    __syncthreads();

    // burst-load this wave's 16 weight fragments (16KB/wave, fully coalesced)
    const u64x2* wp = (const u64x2*)(Wp + so);
    u64x2 wf[16];
#pragma unroll
    for (int i = 0; i < 16; ++i) wf[i] = wp[(size_t)i * 64];

    f32x4 acc = {0.f, 0.f, 0.f, 0.f};
    const char* ab = At + m * 32768;
    int b16 = lane & 15, hi = lane >> 4;
    int loff = (hi & 1) * 8;
#pragma unroll
    for (int kk2 = 0; kk2 < 16; ++kk2) {
        int P0 = 4 * kk2 + (hi >> 1), P1 = P0 + 2;
        long long a0 = *(const long long*)(ab + (P0 * 16 + (b16 ^ (P0 & 15))) * 16 + loff);
        acc = mfma8(a0, (long long)wf[kk2].x, acc);
        long long a1 = *(const long long*)(ab + (P1 * 16 + (b16 ^ (P1 & 15))) * 16 + loff);
        acc = mfma8(a1, (long long)wf[kk2].y, acc);
    }
    int brow = hi * 4;
#pragma unroll
    for (int i = 0; i < 4; ++i) gbuf[w][brow + i][b16] = acc[i];
    __syncthreads();

    if (tid < 128) {
        int b = tid >> 3, f = tid & 7;
        float gv[4];
#pragma unroll
        for (int g = 0; g < 4; ++g) {
            int gpp = g >> 1, jl = ((g & 1) << 3) | f;
            float s = 0.f;
#pragma unroll
            for (int mk = 0; mk < 4; ++mk)
                s += gbuf[gpp + ((mk & 1) << 1) + ((mk >> 1) << 2)][b][jl];
            gv[g] = s * (1.0f / 128.0f) + bia[g];
        }
        float cn = sigm(gv[1]) * cst + sigm(gv[0]) * tanh_f(gv[2]);
        float hn = sigm(gv[3]) * tanh_f(cn);
        cst = cn;
        hdst[(size_t)b * FDIM + col] = (uchar)f2fp8(hn * 4.0f);
        if (odst) odst[(size_t)b * FDIM + col] = f2b(hn);
    }
    gbar(bar, target);
}

__global__ __launch_bounds__(512, 2) void k_lstm(const uchar* __restrict__ Wp,
                                                 const float* __restrict__ bias0,
                                                 const float* __restrict__ bias1,
                                                 const uchar* __restrict__ seqb,
                                                 uchar* __restrict__ h0, uchar* __restrict__ h1,
                                                 u16* __restrict__ seqout, unsigned* __restrict__ bar) {
    __shared__ char At[65536];
    __shared__ float gbuf[8][16][16];
    int tid = threadIdx.x, lane = tid & 63, w = tid >> 6;
    int gp = w & 1, m = (w >> 1) & 1, kh = w >> 2;
    int bl = blockIdx.x;
    size_t so0 = ((((size_t)(0 + m) * 256 + bl) * 2 + gp) * 2 + kh) * 16384 + (size_t)lane * 16;
    size_t so1 = ((((size_t)(2 + m) * 256 + bl) * 2 + gp) * 2 + kh) * 16384 + (size_t)lane * 16;
    int f = tid & 7, col = bl * 8 + f;
    float c0 = 0.f, c1 = 0.f;
    float bia[8];
    if (tid < 128) {
#pragma unroll
        for (int g = 0; g < 4; ++g) {
            bia[g] = bias0[g * FDIM + col];
            bia[4 + g] = bias1[g * FDIM + col];
        }
    }
    const size_t BF = (size_t)16 * FDIM;
    unsigned target = 0;
    for (int st = 0; st < NSTEP; ++st) {
        int cur = st & 1, prv = cur ^ 1;
        const uchar* x0 = (st < 32) ? (seqb + (size_t)st * BF) : (h1 + (size_t)prv * BF);
        target += NBLK;
        do_cell(At, gbuf, Wp, so0, x0, h0 + (size_t)prv * BF,
                h0 + (size_t)cur * BF, nullptr, bia, c0, bar, target, col);
        u16* od = (st >= 31) ? (seqout + (size_t)(st - 31) * BF) : nullptr;
        target += NBLK;
        do_cell(At, gbuf, Wp, so1, h0 + (size_t)cur * BF, h1 + (size_t)prv * BF,
                h1 + (size_t)cur * BF, od, bia + 4, c1, bar, target, col);
    }
}

// ---------------- copy x into top half of output ----------------
__global__ void k_copyx(const float* __restrict__ x, float* __restrict__ out) {
    size_t n = (size_t)4096 * 256;
    size_t stride = (size_t)gridDim.x * blockDim.x;
    for (size_t i = (size_t)blockIdx.x * blockDim.x + threadIdx.x; i < n; i += stride) {
        size_t bc = i >> 8, r = i & 255;
        ((float4*)out)[bc * 512 + r] = ((const float4*)x)[i];
    }
}

// ---------------- output 1x1 conv into bottom half ----------------
__global__ __launch_bounds__(256) void k_convout(const u16* __restrict__ seqout,
                                                 const float* __restrict__ w_out,
                                                 const float* __restrict__ b_out,
                                                 float* __restrict__ out) {
    int s = blockIdx.x >> 4, b = blockIdx.x & 15;
    __shared__ float srow[2048];
    int tid = threadIdx.x;
    for (int i = tid; i < 2048; i += 256) srow[i] = b2f(seqout[((size_t)s * 16 + b) * FDIM + i]);
    __syncthreads();
    int o = tid;
    float bo = b_out[o];
    float wreg[64];
#pragma unroll
    for (int cb = 0; cb < 64; ++cb) wreg[cb] = w_out[o * 64 + cb];
    for (int w4 = 0; w4 < 8; ++w4) {
        float ac0 = bo, ac1 = bo, ac2 = bo, ac3 = bo;
#pragma unroll
        for (int cb = 0; cb < 64; ++cb) {
            float wv = wreg[cb];
            ac0 += srow[(w4 * 4 + 0) * 64 + cb] * wv;
            ac1 += srow[(w4 * 4 + 1) * 64 + cb] * wv;
            ac2 += srow[(w4 * 4 + 2) * 64 + cb] * wv;
            ac3 += srow[(w4 * 4 + 3) * 64 + cb] * wv;
        }
        float4 v; v.x = ac0; v.y = ac1; v.z = ac2; v.w = ac3;
        *(float4*)&out[(((size_t)b * 256 + o) * 64 + 32 + s) * 32 + w4 * 4] = v;
    }
}

extern "C" void kernel_launch(void* const* d_in, const int* in_sizes, int n_in,
                              void* d_out, int out_size, void* d_ws, size_t ws_size,
                              hipStream_t stream) {
    const float* x    = (const float*)d_in[0];
    const float* w_in = (const float*)d_in[1];
    const float* b_in = (const float*)d_in[2];
    const float* Wih0 = (const float*)d_in[3];
    const float* Whh0 = (const float*)d_in[4];
    const float* bih0 = (const float*)d_in[5];
    const float* bhh0 = (const float*)d_in[6];
    const float* Wih1 = (const float*)d_in[7];
    const float* Whh1 = (const float*)d_in[8];
    const float* bih1 = (const float*)d_in[9];
    const float* bhh1 = (const float*)d_in[10];
    const float* wout = (const float*)d_in[11];
    const float* bout = (const float*)d_in[12];
    float* out = (float*)d_out;
    char* ws = (char*)d_ws;

    uchar* Wp = (uchar*)ws;
    size_t off = (size_t)64 * 1024 * 1024;               // 67,108,864 (fp8 packed weights)
    float* bias0 = (float*)(ws + off); off += 4 * FDIM * 4;
    float* bias1 = (float*)(ws + off); off += 4 * FDIM * 4;
    uchar* seqb = (uchar*)(ws + off); off += (size_t)32 * 16 * FDIM;
    u16* seqout = (u16*)(ws + off); off += (size_t)32 * 16 * FDIM * 2;
    size_t zoff = off;
    uchar* h0 = (uchar*)(ws + off); off += (size_t)2 * 16 * FDIM;
    uchar* h1 = (uchar*)(ws + off); off += (size_t)2 * 16 * FDIM;
    unsigned* bar = (unsigned*)(ws + off); off += 256;

    hipMemsetAsync(ws + zoff, 0, off - zoff, stream);

    k_pack<<<8192, 256, 0, stream>>>(Wih0, Whh0, Wih1, Whh1, Wp);
    k_bias<<<32, 256, 0, stream>>>(bih0, bhh0, bih1, bhh1, bias0, bias1);
    k_seqprep<<<512, 256, 0, stream>>>(x, w_in, b_in, seqb);
    k_lstm<<<NBLK, 512, 0, stream>>>(Wp, bias0, bias1, seqb, h0, h1, seqout, bar);
    k_copyx<<<2048, 256, 0, stream>>>(x, out);
    k_convout<<<512, 256, 0, stream>>>(seqout, wout, bout, out);
}